// Round 1
// baseline (1773.274 us; speedup 1.0000x reference)
//
#include <hip/hip_runtime.h>
#include <math.h>

// Problem constants (from reference)
#define Nn 50000
#define Ee 500000
#define Cc 256
#define Hh 128
#define Ll 4
#define Gg 64
#define Kk 8
#define NCc 2

// ---------------- CSR build (dst-sorted edge list) ----------------

__global__ void hist_kernel(const int* __restrict__ dst, int* __restrict__ deg) {
    int e = blockIdx.x * 256 + threadIdx.x;
    if (e < Ee) atomicAdd(&deg[dst[e]], 1);
}

__global__ __launch_bounds__(1024) void scan_kernel(const int* __restrict__ deg,
                                                    int* __restrict__ off,
                                                    int* __restrict__ pos) {
    __shared__ int sc[1024];
    int t = threadIdx.x;
    const int chunk = (Nn + 1023) / 1024;  // 49
    int start = t * chunk;
    int end = min(start + chunk, Nn);
    int s = 0;
    for (int i = start; i < end; i++) s += deg[i];
    sc[t] = s;
    __syncthreads();
    // Hillis-Steele inclusive scan
    for (int o = 1; o < 1024; o <<= 1) {
        int v = (t >= o) ? sc[t - o] : 0;
        __syncthreads();
        sc[t] += v;
        __syncthreads();
    }
    int base = (t == 0) ? 0 : sc[t - 1];
    for (int i = start; i < end; i++) {
        off[i] = base;
        pos[i] = base;
        base += deg[i];
    }
    if (t == 1023) off[Nn] = sc[1023];
}

__global__ void scatter_kernel(const int* __restrict__ src, const int* __restrict__ dst,
                               const float* __restrict__ attr, int* __restrict__ pos,
                               int* __restrict__ ssrc, float* __restrict__ sattr) {
    int e = blockIdx.x * 256 + threadIdx.x;
    if (e < Ee) {
        int d = dst[e];
        int p = atomicAdd(&pos[d], 1);
        ssrc[p] = src[e];
        sattr[p] = attr[e];
    }
}

// ---------------- Tiled fp32 GEMM: C = A[M,K] @ B[K,N] (+bias, +BN/ReLU, +=) ----------
// flags bit0: BN+ReLU epilogue; bit1: accumulate into Cout

#define TM 128
#define TN 64
#define TK 16

__global__ __launch_bounds__(256) void gemm_kernel(
    const float* __restrict__ A, const float* __restrict__ B,
    const float* __restrict__ bias,
    const float* __restrict__ bn_g, const float* __restrict__ bn_b,
    const float* __restrict__ bn_m, const float* __restrict__ bn_v,
    float* __restrict__ Cout, int M, int N, int K, int flags) {
    __shared__ float As[TK][TM];  // 8 KB, k-major for stride-1 row reads
    __shared__ float Bs[TK][TN];  // 4 KB
    int tid = threadIdx.x;
    int tx = tid & 15, ty = tid >> 4;
    int m0 = blockIdx.y * TM;
    int n0 = blockIdx.x * TN;
    float acc[8][4];
#pragma unroll
    for (int i = 0; i < 8; i++)
#pragma unroll
        for (int j = 0; j < 4; j++) acc[i][j] = 0.f;

    for (int k0 = 0; k0 < K; k0 += TK) {
        // Load A tile: 128 rows x 16 k = 512 float4, 2 per thread (transpose to k-major)
#pragma unroll
        for (int l = 0; l < 2; l++) {
            int fi = tid + l * 256;
            int row = fi >> 2;
            int kq = (fi & 3) * 4;
            int gr = m0 + row;
            float4 v = make_float4(0.f, 0.f, 0.f, 0.f);
            if (gr < M) v = *(const float4*)(A + (size_t)gr * K + k0 + kq);
            As[kq + 0][row] = v.x;
            As[kq + 1][row] = v.y;
            As[kq + 2][row] = v.z;
            As[kq + 3][row] = v.w;
        }
        // Load B tile: 16 rows x 64 = 256 float4, 1 per thread
        {
            int row = tid >> 4;
            int nq = (tid & 15) * 4;
            float4 v = *(const float4*)(B + (size_t)(k0 + row) * N + n0 + nq);
            *(float4*)&Bs[row][nq] = v;
        }
        __syncthreads();
#pragma unroll
        for (int kk = 0; kk < TK; kk++) {
            float a[8], b[4];
#pragma unroll
            for (int i = 0; i < 8; i++) a[i] = As[kk][ty * 8 + i];
#pragma unroll
            for (int j = 0; j < 4; j++) b[j] = Bs[kk][tx * 4 + j];
#pragma unroll
            for (int i = 0; i < 8; i++)
#pragma unroll
                for (int j = 0; j < 4; j++) acc[i][j] = fmaf(a[i], b[j], acc[i][j]);
        }
        __syncthreads();
    }
    // Epilogue
#pragma unroll
    for (int j = 0; j < 4; j++) {
        int gc = n0 + tx * 4 + j;
        float bs = bias ? bias[gc] : 0.f;
        float g = 1.f, bb = 0.f, mm = 0.f, inv = 1.f;
        if (flags & 1) {
            g = bn_g[gc];
            bb = bn_b[gc];
            mm = bn_m[gc];
            inv = rsqrtf(bn_v[gc] + 1e-5f);
        }
#pragma unroll
        for (int i = 0; i < 8; i++) {
            int gr = m0 + ty * 8 + i;
            if (gr < M) {
                float v = acc[i][j] + bs;
                if (flags & 1) {
                    v = g * (v - mm) * inv + bb;
                    v = fmaxf(v, 0.f);
                }
                size_t idx = (size_t)gr * N + gc;
                if (flags & 2)
                    Cout[idx] += v;
                else
                    Cout[idx] = v;
            }
        }
    }
}

// ---------------- Fused GENConv softmax aggregation ----------------
// One block (128 threads = feature lanes) per dst node. Two passes over its
// in-edges: max, then exp-sum. msg>0 so empty segments -> agg 0 matches ref.

__global__ __launch_bounds__(128) void agg_kernel(
    const float* __restrict__ xs, const float* __restrict__ xd,
    const int* __restrict__ ssrc, const float* __restrict__ sattr,
    const int* __restrict__ off,
    const float* __restrict__ ew, const float* __restrict__ eb,
    const float* __restrict__ tptr, float* __restrict__ out) {
    int d = blockIdx.x;
    int hh = threadIdx.x;
    int s0 = off[d], s1 = off[d + 1];
    float w = ew[hh], b = eb[hh];
    float tl = tptr[0];
    float zmax = -INFINITY;
    for (int j = s0; j < s1; j++) {
        int s = ssrc[j];
        float a = sattr[j];
        float m = fmaxf(xs[(size_t)s * Hh + hh] + a * w + b, 0.f) + 1e-7f;
        zmax = fmaxf(zmax, m * tl);
    }
    float denom = 0.f, num = 0.f;
    for (int j = s0; j < s1; j++) {
        int s = ssrc[j];
        float a = sattr[j];
        float m = fmaxf(xs[(size_t)s * Hh + hh] + a * w + b, 0.f) + 1e-7f;
        float ez = __expf(m * tl - zmax);
        denom += ez;
        num = fmaf(m, ez, num);
    }
    float agg = (s1 > s0) ? (num / fmaxf(denom, 1e-16f)) : 0.f;
    out[(size_t)d * Hh + hh] = agg + xd[(size_t)d * Hh + hh];
}

// ---------------- res+ pre-norm: r = relu(BN(h)) ----------------

__global__ void prenorm_kernel(const float* __restrict__ h, const float* __restrict__ g,
                               const float* __restrict__ b, const float* __restrict__ m,
                               const float* __restrict__ v, float* __restrict__ r) {
    int idx = blockIdx.x * 256 + threadIdx.x;
    if (idx < Nn * Hh) {
        int hh = idx & (Hh - 1);
        float val = h[idx];
        val = g[hh] * (val - m[hh]) * rsqrtf(v[hh] + 1e-5f) + b[hh];
        r[idx] = fmaxf(val, 0.f);
    }
}

// ---------------- final norm + mean-pool (atomic) ----------------

__global__ void pool_kernel(const float* __restrict__ h, const int* __restrict__ batch,
                            const float* __restrict__ g, const float* __restrict__ b,
                            const float* __restrict__ m, const float* __restrict__ v,
                            float* __restrict__ pooled, float* __restrict__ cnt) {
    int idx = blockIdx.x * 256 + threadIdx.x;
    if (idx < Nn * Hh) {
        int hh = idx & (Hh - 1);
        int i = idx >> 7;
        float val = h[idx];
        val = fmaxf(g[hh] * (val - m[hh]) * rsqrtf(v[hh] + 1e-5f) + b[hh], 0.f);
        int gid = batch[i];
        atomicAdd(&pooled[(size_t)gid * Hh + hh], val);
        if (hh == 0) atomicAdd(&cnt[gid], 1.f);
    }
}

// ---------------- classifier: [G, H+K] @ [H+K, NC] + b ----------------

__global__ __launch_bounds__(128) void cls_kernel(const float* __restrict__ pooled,
                                                  const float* __restrict__ cnt,
                                                  const float* __restrict__ clinical,
                                                  const float* __restrict__ w,
                                                  const float* __restrict__ bias,
                                                  float* __restrict__ out) {
    int t = threadIdx.x;  // 128 = 64 graphs x 2 classes
    int g = t >> 1, c = t & 1;
    float inv = 1.f / fmaxf(cnt[g], 1.f);
    float s = bias[c];
    for (int j = 0; j < Hh; j++) s += pooled[g * Hh + j] * inv * w[j * NCc + c];
    for (int k = 0; k < Kk; k++) s += clinical[g * Kk + k] * w[(Hh + k) * NCc + c];
    out[g * NCc + c] = s;
}

// ---------------- launch ----------------

extern "C" void kernel_launch(void* const* d_in, const int* in_sizes, int n_in,
                              void* d_out, int out_size, void* d_ws, size_t ws_size,
                              hipStream_t stream) {
    const float* x = (const float*)d_in[0];
    const int* eidx = (const int*)d_in[1];
    const float* eattr = (const float*)d_in[2];
    const int* batch = (const int*)d_in[3];
    const float* clinical = (const float*)d_in[4];
    const float* lin_src_w = (const float*)d_in[5];
    const float* lin_src_b = (const float*)d_in[6];
    const float* lin_dst_w = (const float*)d_in[7];
    const float* lin_dst_b = (const float*)d_in[8];
    const float* edge_w = (const float*)d_in[9];
    const float* edge_b = (const float*)d_in[10];
    const float* tt = (const float*)d_in[11];
    const float* mlp_w1 = (const float*)d_in[12];
    const float* mlp_b1 = (const float*)d_in[13];
    const float* bn_g = (const float*)d_in[14];
    const float* bn_b = (const float*)d_in[15];
    const float* bn_m = (const float*)d_in[16];
    const float* bn_v = (const float*)d_in[17];
    const float* mlp_w2 = (const float*)d_in[18];
    const float* mlp_b2 = (const float*)d_in[19];
    const float* norm_g = (const float*)d_in[20];
    const float* norm_b = (const float*)d_in[21];
    const float* norm_m = (const float*)d_in[22];
    const float* norm_v = (const float*)d_in[23];
    const float* cls_w = (const float*)d_in[24];
    const float* cls_b = (const float*)d_in[25];
    float* out = (float*)d_out;

    const int* src = eidx;
    const int* dst = eidx + Ee;

    // Workspace carve-up (~160 MB total)
    char* ws = (char*)d_ws;
    size_t off_b = 0;
    auto alloc = [&](size_t bytes) -> void* {
        void* p = ws + off_b;
        off_b += (bytes + 255) & ~(size_t)255;
        return p;
    };
    float* xs = (float*)alloc((size_t)Nn * Hh * 4);      // also reused as r for l>=1
    float* xd = (float*)alloc((size_t)Nn * Hh * 4);
    float* hbuf = (float*)alloc((size_t)Nn * Hh * 4);
    float* aggout = (float*)alloc((size_t)Nn * Hh * 4);
    float* hmid = (float*)alloc((size_t)Nn * 2 * Hh * 4);
    int* deg = (int*)alloc((Nn + 1) * 4);
    int* offp = (int*)alloc((Nn + 1) * 4);
    int* pos = (int*)alloc((size_t)Nn * 4);
    int* ssrc = (int*)alloc((size_t)Ee * 4);
    float* sattr = (float*)alloc((size_t)Ee * 4);
    float* pooled = (float*)alloc((size_t)Gg * Hh * 4);
    float* cntb = (float*)alloc(Gg * 4);

    // CSR build (every call — edge_index is restored pristine each launch)
    hipMemsetAsync(deg, 0, (Nn + 1) * 4, stream);
    hipMemsetAsync(pooled, 0, (size_t)Gg * Hh * 4, stream);
    hipMemsetAsync(cntb, 0, Gg * 4, stream);
    hist_kernel<<<(Ee + 255) / 256, 256, 0, stream>>>(dst, deg);
    scan_kernel<<<1, 1024, 0, stream>>>(deg, offp, pos);
    scatter_kernel<<<(Ee + 255) / 256, 256, 0, stream>>>(src, dst, eattr, pos, ssrc, sattr);

    // Input projections: xs = x@Wsrc+b, xd = x@Wdst+b
    dim3 gproj(Hh / TN, (Nn + TM - 1) / TM);
    gemm_kernel<<<gproj, 256, 0, stream>>>(x, lin_src_w, lin_src_b, nullptr, nullptr, nullptr,
                                           nullptr, xs, Nn, Hh, Cc, 0);
    gemm_kernel<<<gproj, 256, 0, stream>>>(x, lin_dst_w, lin_dst_b, nullptr, nullptr, nullptr,
                                           nullptr, xd, Nn, Hh, Cc, 0);

    for (int l = 0; l < Ll; l++) {
        const float* cxs;
        const float* cxd;
        if (l == 0) {
            cxs = xs;
            cxd = xd;
        } else {
            prenorm_kernel<<<(Nn * Hh + 255) / 256, 256, 0, stream>>>(
                hbuf, norm_g + l * Hh, norm_b + l * Hh, norm_m + l * Hh, norm_v + l * Hh, xs);
            cxs = xs;
            cxd = xs;
        }
        agg_kernel<<<Nn, 128, 0, stream>>>(cxs, cxd, ssrc, sattr, offp, edge_w + l * Hh,
                                           edge_b + l * Hh, tt + l, aggout);
        dim3 g1((2 * Hh) / TN, (Nn + TM - 1) / TM);
        gemm_kernel<<<g1, 256, 0, stream>>>(aggout, mlp_w1 + (size_t)l * Hh * 2 * Hh,
                                            mlp_b1 + l * 2 * Hh, bn_g + l * 2 * Hh,
                                            bn_b + l * 2 * Hh, bn_m + l * 2 * Hh,
                                            bn_v + l * 2 * Hh, hmid, Nn, 2 * Hh, Hh, 1);
        dim3 g2(Hh / TN, (Nn + TM - 1) / TM);
        gemm_kernel<<<g2, 256, 0, stream>>>(hmid, mlp_w2 + (size_t)l * 2 * Hh * Hh,
                                            mlp_b2 + l * Hh, nullptr, nullptr, nullptr, nullptr,
                                            hbuf, Nn, Hh, 2 * Hh, (l == 0) ? 0 : 2);
    }

    // Final norm (layer-0 params) + mean pool + classifier
    pool_kernel<<<(Nn * Hh + 255) / 256, 256, 0, stream>>>(hbuf, batch, norm_g, norm_b, norm_m,
                                                           norm_v, pooled, cntb);
    cls_kernel<<<1, 128, 0, stream>>>(pooled, cntb, clinical, cls_w, cls_b, out);
}

// Round 2
// 866.159 us; speedup vs baseline: 2.0473x; 2.0473x over previous
//
#include <hip/hip_runtime.h>
#include <math.h>

// Problem constants (from reference)
#define Nn 50000
#define Ee 500000
#define Cc 256
#define Hh 128
#define Ll 4
#define Gg 64
#define Kk 8
#define NCc 2

typedef __attribute__((ext_vector_type(8))) short short8;
typedef __attribute__((ext_vector_type(4))) float f32x4;

__device__ __forceinline__ unsigned short f2bf(float f) {
    union { float f; unsigned int u; } v;
    v.f = f;
    unsigned int u = v.u;
    return (unsigned short)((u + 0x7FFFu + ((u >> 16) & 1u)) >> 16);
}

// ---------------- CSR build (dst-sorted edge list) ----------------

__global__ void hist_kernel(const int* __restrict__ dst, int* __restrict__ deg) {
    int e = blockIdx.x * 256 + threadIdx.x;
    if (e < Ee) atomicAdd(&deg[dst[e]], 1);
}

__global__ __launch_bounds__(1024) void scan_kernel(const int* __restrict__ deg,
                                                    int* __restrict__ off,
                                                    int* __restrict__ pos) {
    __shared__ int sc[1024];
    int t = threadIdx.x;
    const int chunk = (Nn + 1023) / 1024;  // 49
    int start = t * chunk;
    int end = min(start + chunk, Nn);
    int s = 0;
    for (int i = start; i < end; i++) s += deg[i];
    sc[t] = s;
    __syncthreads();
    for (int o = 1; o < 1024; o <<= 1) {
        int v = (t >= o) ? sc[t - o] : 0;
        __syncthreads();
        sc[t] += v;
        __syncthreads();
    }
    int base = (t == 0) ? 0 : sc[t - 1];
    for (int i = start; i < end; i++) {
        off[i] = base;
        pos[i] = base;
        base += deg[i];
    }
    if (t == 1023) off[Nn] = sc[1023];
}

__global__ void scatter_kernel(const int* __restrict__ src, const int* __restrict__ dst,
                               const float* __restrict__ attr, int* __restrict__ pos,
                               int* __restrict__ ssrc, float* __restrict__ sattr) {
    int e = blockIdx.x * 256 + threadIdx.x;
    if (e < Ee) {
        int d = dst[e];
        int p = atomicAdd(&pos[d], 1);
        ssrc[p] = src[e];
        sattr[p] = attr[e];
    }
}

// ---------------- weight convert + transpose to bf16 [N][K] ----------------
// segments (each 32768 elems): 0=lin_src, 1=lin_dst, 2..5=mlp_w1[l], 6..9=mlp_w2[l]

__global__ void wconv_kernel(const float* __restrict__ lin_src_w,
                             const float* __restrict__ lin_dst_w,
                             const float* __restrict__ mlp_w1,
                             const float* __restrict__ mlp_w2,
                             unsigned short* __restrict__ wt) {
    int s = blockIdx.y;
    int e = blockIdx.x * 256 + threadIdx.x;  // 0..32767
    unsigned short* dst = wt + (size_t)s * 32768;
    if (s < 2) {
        const float* src = s ? lin_dst_w : lin_src_w;  // [256][128]
        int k = e >> 7, n = e & 127;
        dst[n * 256 + k] = f2bf(src[e]);
    } else if (s < 6) {
        const float* src = mlp_w1 + (size_t)(s - 2) * 32768;  // [128][256]
        int k = e >> 8, n = e & 255;
        dst[n * 128 + k] = f2bf(src[e]);
    } else {
        const float* src = mlp_w2 + (size_t)(s - 6) * 32768;  // [256][128]
        int k = e >> 7, n = e & 127;
        dst[n * 256 + k] = f2bf(src[e]);
    }
}

// ---------------- bf16 MFMA GEMM: C[M,N] = A[M,K](fp32) @ B (bf16, [N][K]) ----------
// flags bit0: BN+ReLU epilogue; bit1: accumulate into Cout

#define BM 128
#define BN 64
#define BK 32
#define LDA 40  // padded row (bf16 elems): stride 80B = 20 banks -> 2-way max (free)
#define LDB 40

__global__ __launch_bounds__(256) void gemm_bf16_kernel(
    const float* __restrict__ A, const unsigned short* __restrict__ Bt,
    const float* __restrict__ bias,
    const float* __restrict__ bn_g, const float* __restrict__ bn_b,
    const float* __restrict__ bn_m, const float* __restrict__ bn_v,
    float* __restrict__ Cout, int M, int N, int K, int flags) {
    __shared__ __align__(16) unsigned short As[BM * LDA];  // 10240 B
    __shared__ __align__(16) unsigned short Bs[BN * LDB];  // 5120 B
    int tid = threadIdx.x;
    int m0 = blockIdx.y * BM, n0 = blockIdx.x * BN;
    int wave = tid >> 6, lane = tid & 63;
    int wr = wave >> 1, wc = wave & 1;  // 2x2 wave grid: 64 rows x 32 cols each
    int lrow = lane & 15, quad = lane >> 4;

    f32x4 acc[4][2];
#pragma unroll
    for (int i = 0; i < 4; i++)
#pragma unroll
        for (int j = 0; j < 2; j++) acc[i][j] = (f32x4){0.f, 0.f, 0.f, 0.f};

    // A staging coords: 2 threads per row, 16 fp32 each
    int arow = tid >> 1, akb = (tid & 1) * 16;
    // B staging coords: 4 threads per n-row, 8 bf16 each
    int bn_ = tid >> 2, bkb = (tid & 3) * 8;

    for (int k0 = 0; k0 < K; k0 += BK) {
        // ---- stage A (fp32 -> bf16) ----
        {
            int gr = m0 + arow;
            unsigned short tmp[16];
            if (gr < M) {
                const float* ap = A + (size_t)gr * K + k0 + akb;
                float4 v0 = ((const float4*)ap)[0];
                float4 v1 = ((const float4*)ap)[1];
                float4 v2 = ((const float4*)ap)[2];
                float4 v3 = ((const float4*)ap)[3];
                tmp[0] = f2bf(v0.x); tmp[1] = f2bf(v0.y); tmp[2] = f2bf(v0.z); tmp[3] = f2bf(v0.w);
                tmp[4] = f2bf(v1.x); tmp[5] = f2bf(v1.y); tmp[6] = f2bf(v1.z); tmp[7] = f2bf(v1.w);
                tmp[8] = f2bf(v2.x); tmp[9] = f2bf(v2.y); tmp[10] = f2bf(v2.z); tmp[11] = f2bf(v2.w);
                tmp[12] = f2bf(v3.x); tmp[13] = f2bf(v3.y); tmp[14] = f2bf(v3.z); tmp[15] = f2bf(v3.w);
            } else {
#pragma unroll
                for (int i = 0; i < 16; i++) tmp[i] = 0;
            }
            *(float4*)&As[arow * LDA + akb] = *(float4*)&tmp[0];
            *(float4*)&As[arow * LDA + akb + 8] = *(float4*)&tmp[8];
        }
        // ---- stage B (bf16 straight copy, [N][K] layout) ----
        {
            const unsigned short* bp = Bt + (size_t)(n0 + bn_) * K + k0 + bkb;
            *(float4*)&Bs[bn_ * LDB + bkb] = *(const float4*)bp;
        }
        __syncthreads();
        // ---- fragments + MFMA ----
        short8 af[4], bf[2];
#pragma unroll
        for (int mt = 0; mt < 4; mt++) {
            int m = wr * 64 + mt * 16 + lrow;
            af[mt] = *(const short8*)&As[m * LDA + quad * 8];
        }
#pragma unroll
        for (int nt = 0; nt < 2; nt++) {
            int n = wc * 32 + nt * 16 + lrow;
            bf[nt] = *(const short8*)&Bs[n * LDB + quad * 8];
        }
#pragma unroll
        for (int mt = 0; mt < 4; mt++)
#pragma unroll
            for (int nt = 0; nt < 2; nt++)
                acc[mt][nt] = __builtin_amdgcn_mfma_f32_16x16x32_bf16(af[mt], bf[nt],
                                                                     acc[mt][nt], 0, 0, 0);
        __syncthreads();
    }

    // ---- epilogue ----
#pragma unroll
    for (int nt = 0; nt < 2; nt++) {
        int gc = n0 + wc * 32 + nt * 16 + lrow;
        float bs = bias ? bias[gc] : 0.f;
        float g = 1.f, bb = 0.f, mm = 0.f, inv = 1.f;
        if (flags & 1) {
            g = bn_g[gc];
            bb = bn_b[gc];
            mm = bn_m[gc];
            inv = rsqrtf(bn_v[gc] + 1e-5f);
        }
#pragma unroll
        for (int mt = 0; mt < 4; mt++) {
#pragma unroll
            for (int r = 0; r < 4; r++) {
                int gr = m0 + wr * 64 + mt * 16 + quad * 4 + r;
                if (gr < M) {
                    float v = acc[mt][nt][r] + bs;
                    if (flags & 1) {
                        v = g * (v - mm) * inv + bb;
                        v = fmaxf(v, 0.f);
                    }
                    size_t idx = (size_t)gr * N + gc;
                    if (flags & 2)
                        Cout[idx] += v;
                    else
                        Cout[idx] = v;
                }
            }
        }
    }
}

// ---------------- Fused GENConv aggregation: one-pass online softmax ----------------
// One block (128 feature lanes) per dst node; unroll-4 edge prefetch.

__global__ __launch_bounds__(128) void agg_kernel(
    const float* __restrict__ xs, const float* __restrict__ xd,
    const int* __restrict__ ssrc, const float* __restrict__ sattr,
    const int* __restrict__ off,
    const float* __restrict__ ew, const float* __restrict__ eb,
    const float* __restrict__ tptr, float* __restrict__ out) {
    int d = blockIdx.x;
    int hh = threadIdx.x;
    int s0 = off[d], s1 = off[d + 1];
    float w = ew[hh], b = eb[hh];
    float tl = tptr[0];
    float mmax = -INFINITY, denom = 0.f, num = 0.f;

#define EDGE_STEP(xv, av)                                          \
    {                                                              \
        float msg = fmaxf((xv) + (av)*w + b, 0.f) + 1e-7f;         \
        float z = msg * tl;                                        \
        float nm = fmaxf(mmax, z);                                 \
        float c = __expf(mmax - nm);                               \
        float e = __expf(z - nm);                                  \
        denom = denom * c + e;                                     \
        num = num * c + msg * e;                                   \
        mmax = nm;                                                 \
    }

    int j = s0;
    for (; j + 3 < s1; j += 4) {
        int i0 = ssrc[j], i1 = ssrc[j + 1], i2 = ssrc[j + 2], i3 = ssrc[j + 3];
        float a0 = sattr[j], a1 = sattr[j + 1], a2 = sattr[j + 2], a3 = sattr[j + 3];
        float x0 = xs[(size_t)i0 * Hh + hh];
        float x1 = xs[(size_t)i1 * Hh + hh];
        float x2 = xs[(size_t)i2 * Hh + hh];
        float x3 = xs[(size_t)i3 * Hh + hh];
        EDGE_STEP(x0, a0)
        EDGE_STEP(x1, a1)
        EDGE_STEP(x2, a2)
        EDGE_STEP(x3, a3)
    }
    for (; j < s1; j++) {
        int s = ssrc[j];
        float a = sattr[j];
        float xv = xs[(size_t)s * Hh + hh];
        EDGE_STEP(xv, a)
    }
    float agg = (s1 > s0) ? (num / fmaxf(denom, 1e-16f)) : 0.f;
    out[(size_t)d * Hh + hh] = agg + xd[(size_t)d * Hh + hh];
#undef EDGE_STEP
}

// ---------------- res+ pre-norm: r = relu(BN(h)) ----------------

__global__ void prenorm_kernel(const float* __restrict__ h, const float* __restrict__ g,
                               const float* __restrict__ b, const float* __restrict__ m,
                               const float* __restrict__ v, float* __restrict__ r) {
    int idx = blockIdx.x * 256 + threadIdx.x;
    if (idx < Nn * Hh) {
        int hh = idx & (Hh - 1);
        float val = h[idx];
        val = g[hh] * (val - m[hh]) * rsqrtf(v[hh] + 1e-5f) + b[hh];
        r[idx] = fmaxf(val, 0.f);
    }
}

// ---------------- final norm + hierarchical mean-pool ----------------
// batch is sorted: accumulate per-graph run in registers, flush one atomic
// per (graph boundary x feature). 6.4M atomics -> ~130k.

#define PCHUNK 100

__global__ __launch_bounds__(128) void pool_kernel(
    const float* __restrict__ h, const int* __restrict__ batch,
    const float* __restrict__ g, const float* __restrict__ b,
    const float* __restrict__ m, const float* __restrict__ v,
    float* __restrict__ pooled, float* __restrict__ cnt) {
    int hh = threadIdx.x;
    int i0 = blockIdx.x * PCHUNK;
    int i1 = min(i0 + PCHUNK, Nn);
    if (i0 >= Nn) return;
    float gg = g[hh], bb = b[hh], mm = m[hh], inv = rsqrtf(v[hh] + 1e-5f);
    int cur = batch[i0];
    float sum = 0.f, c = 0.f;
    for (int i = i0; i < i1; i++) {
        int gid = batch[i];
        float val = fmaxf(gg * (h[(size_t)i * Hh + hh] - mm) * inv + bb, 0.f);
        if (gid != cur) {
            atomicAdd(&pooled[(size_t)cur * Hh + hh], sum);
            if (hh == 0) atomicAdd(&cnt[cur], c);
            cur = gid;
            sum = 0.f;
            c = 0.f;
        }
        sum += val;
        c += 1.f;
    }
    atomicAdd(&pooled[(size_t)cur * Hh + hh], sum);
    if (hh == 0) atomicAdd(&cnt[cur], c);
}

// ---------------- classifier ----------------

__global__ __launch_bounds__(128) void cls_kernel(const float* __restrict__ pooled,
                                                  const float* __restrict__ cnt,
                                                  const float* __restrict__ clinical,
                                                  const float* __restrict__ w,
                                                  const float* __restrict__ bias,
                                                  float* __restrict__ out) {
    int t = threadIdx.x;
    int g = t >> 1, c = t & 1;
    float inv = 1.f / fmaxf(cnt[g], 1.f);
    float s = bias[c];
    for (int j = 0; j < Hh; j++) s += pooled[g * Hh + j] * inv * w[j * NCc + c];
    for (int k = 0; k < Kk; k++) s += clinical[g * Kk + k] * w[(Hh + k) * NCc + c];
    out[g * NCc + c] = s;
}

// ---------------- launch ----------------

extern "C" void kernel_launch(void* const* d_in, const int* in_sizes, int n_in,
                              void* d_out, int out_size, void* d_ws, size_t ws_size,
                              hipStream_t stream) {
    const float* x = (const float*)d_in[0];
    const int* eidx = (const int*)d_in[1];
    const float* eattr = (const float*)d_in[2];
    const int* batch = (const int*)d_in[3];
    const float* clinical = (const float*)d_in[4];
    const float* lin_src_w = (const float*)d_in[5];
    const float* lin_src_b = (const float*)d_in[6];
    const float* lin_dst_w = (const float*)d_in[7];
    const float* lin_dst_b = (const float*)d_in[8];
    const float* edge_w = (const float*)d_in[9];
    const float* edge_b = (const float*)d_in[10];
    const float* tt = (const float*)d_in[11];
    const float* mlp_w1 = (const float*)d_in[12];
    const float* mlp_b1 = (const float*)d_in[13];
    const float* bn_g = (const float*)d_in[14];
    const float* bn_b = (const float*)d_in[15];
    const float* bn_m = (const float*)d_in[16];
    const float* bn_v = (const float*)d_in[17];
    const float* mlp_w2 = (const float*)d_in[18];
    const float* mlp_b2 = (const float*)d_in[19];
    const float* norm_g = (const float*)d_in[20];
    const float* norm_b = (const float*)d_in[21];
    const float* norm_m = (const float*)d_in[22];
    const float* norm_v = (const float*)d_in[23];
    const float* cls_w = (const float*)d_in[24];
    const float* cls_b = (const float*)d_in[25];
    float* out = (float*)d_out;

    const int* src = eidx;
    const int* dst = eidx + Ee;

    char* ws = (char*)d_ws;
    size_t off_b = 0;
    auto alloc = [&](size_t bytes) -> void* {
        void* p = ws + off_b;
        off_b += (bytes + 255) & ~(size_t)255;
        return p;
    };
    float* xs = (float*)alloc((size_t)Nn * Hh * 4);  // reused as r for l>=1
    float* xd = (float*)alloc((size_t)Nn * Hh * 4);
    float* hbuf = (float*)alloc((size_t)Nn * Hh * 4);
    float* aggout = (float*)alloc((size_t)Nn * Hh * 4);
    float* hmid = (float*)alloc((size_t)Nn * 2 * Hh * 4);
    int* deg = (int*)alloc((Nn + 1) * 4);
    int* offp = (int*)alloc((Nn + 1) * 4);
    int* pos = (int*)alloc((size_t)Nn * 4);
    int* ssrc = (int*)alloc((size_t)Ee * 4);
    float* sattr = (float*)alloc((size_t)Ee * 4);
    float* pooled = (float*)alloc((size_t)Gg * Hh * 4);
    float* cntb = (float*)alloc(Gg * 4);
    unsigned short* wt = (unsigned short*)alloc((size_t)10 * 32768 * 2);

    hipMemsetAsync(deg, 0, (Nn + 1) * 4, stream);
    hipMemsetAsync(pooled, 0, (size_t)Gg * Hh * 4, stream);
    hipMemsetAsync(cntb, 0, Gg * 4, stream);
    hist_kernel<<<(Ee + 255) / 256, 256, 0, stream>>>(dst, deg);
    scan_kernel<<<1, 1024, 0, stream>>>(deg, offp, pos);
    scatter_kernel<<<(Ee + 255) / 256, 256, 0, stream>>>(src, dst, eattr, pos, ssrc, sattr);
    wconv_kernel<<<dim3(128, 10), 256, 0, stream>>>(lin_src_w, lin_dst_w, mlp_w1, mlp_w2, wt);

    const unsigned short* wt_src = wt;
    const unsigned short* wt_dst = wt + 32768;
    const unsigned short* wt_w1 = wt + 2 * 32768;
    const unsigned short* wt_w2 = wt + 6 * 32768;

    // Input projections
    dim3 gproj(Hh / BN, (Nn + BM - 1) / BM);
    gemm_bf16_kernel<<<gproj, 256, 0, stream>>>(x, wt_src, lin_src_b, nullptr, nullptr, nullptr,
                                                nullptr, xs, Nn, Hh, Cc, 0);
    gemm_bf16_kernel<<<gproj, 256, 0, stream>>>(x, wt_dst, lin_dst_b, nullptr, nullptr, nullptr,
                                                nullptr, xd, Nn, Hh, Cc, 0);

    for (int l = 0; l < Ll; l++) {
        const float* cxs;
        const float* cxd;
        if (l == 0) {
            cxs = xs;
            cxd = xd;
        } else {
            prenorm_kernel<<<(Nn * Hh + 255) / 256, 256, 0, stream>>>(
                hbuf, norm_g + l * Hh, norm_b + l * Hh, norm_m + l * Hh, norm_v + l * Hh, xs);
            cxs = xs;
            cxd = xs;
        }
        agg_kernel<<<Nn, 128, 0, stream>>>(cxs, cxd, ssrc, sattr, offp, edge_w + l * Hh,
                                           edge_b + l * Hh, tt + l, aggout);
        dim3 g1((2 * Hh) / BN, (Nn + BM - 1) / BM);
        gemm_bf16_kernel<<<g1, 256, 0, stream>>>(aggout, wt_w1 + (size_t)l * 32768,
                                                 mlp_b1 + l * 2 * Hh, bn_g + l * 2 * Hh,
                                                 bn_b + l * 2 * Hh, bn_m + l * 2 * Hh,
                                                 bn_v + l * 2 * Hh, hmid, Nn, 2 * Hh, Hh, 1);
        dim3 g2(Hh / BN, (Nn + BM - 1) / BM);
        gemm_bf16_kernel<<<g2, 256, 0, stream>>>(hmid, wt_w2 + (size_t)l * 32768,
                                                 mlp_b2 + l * Hh, nullptr, nullptr, nullptr,
                                                 nullptr, hbuf, Nn, Hh, 2 * Hh,
                                                 (l == 0) ? 0 : 2);
    }

    pool_kernel<<<(Nn + PCHUNK - 1) / PCHUNK, 128, 0, stream>>>(hbuf, batch, norm_g, norm_b,
                                                                norm_m, norm_v, pooled, cntb);
    cls_kernel<<<1, 128, 0, stream>>>(pooled, cntb, clinical, cls_w, cls_b, out);
}

// Round 3
// 673.777 us; speedup vs baseline: 2.6318x; 1.2855x over previous
//
#include <hip/hip_runtime.h>
#include <math.h>

// Problem constants (from reference)
#define Nn 50000
#define Ee 500000
#define Cc 256
#define Hh 128
#define Ll 4
#define Gg 64
#define Kk 8
#define NCc 2

#define NB 196  // ceil(Nn/256)

typedef __attribute__((ext_vector_type(8))) short short8;
typedef __attribute__((ext_vector_type(4))) float f32x4;

__device__ __forceinline__ unsigned short f2bf(float f) {
    union { float f; unsigned int u; } v;
    v.f = f;
    unsigned int u = v.u;
    return (unsigned short)((u + 0x7FFFu + ((u >> 16) & 1u)) >> 16);
}
__device__ __forceinline__ float bf2f(unsigned short s) {
    union { float f; unsigned int u; } v;
    v.u = ((unsigned int)s) << 16;
    return v.f;
}

// ---------------- CSR build ----------------

__global__ void hist_kernel(const int* __restrict__ dst, int* __restrict__ deg) {
    int e = blockIdx.x * 256 + threadIdx.x;
    if (e < Ee) atomicAdd(&deg[dst[e]], 1);
}

__global__ __launch_bounds__(256) void bsum_kernel(const int* __restrict__ deg,
                                                   int* __restrict__ bsum) {
    __shared__ int ws[4];
    int t = threadIdx.x;
    int i = blockIdx.x * 256 + t;
    int v = (i < Nn) ? deg[i] : 0;
#pragma unroll
    for (int o = 32; o; o >>= 1) v += __shfl_down(v, o, 64);
    if ((t & 63) == 0) ws[t >> 6] = v;
    __syncthreads();
    if (t == 0) bsum[blockIdx.x] = ws[0] + ws[1] + ws[2] + ws[3];
}

__global__ __launch_bounds__(256) void bscan_kernel(const int* __restrict__ bsum,
                                                    int* __restrict__ boff,
                                                    int* __restrict__ off) {
    __shared__ int sc[256];
    int t = threadIdx.x;
    int v = (t < NB) ? bsum[t] : 0;
    sc[t] = v;
    __syncthreads();
    for (int o = 1; o < 256; o <<= 1) {
        int u = (t >= o) ? sc[t - o] : 0;
        __syncthreads();
        sc[t] += u;
        __syncthreads();
    }
    if (t < NB) boff[t] = sc[t] - v;  // exclusive
    if (t == NB - 1) off[Nn] = sc[t];
}

__global__ __launch_bounds__(256) void offsets_kernel(const int* __restrict__ deg,
                                                      const int* __restrict__ boff,
                                                      int* __restrict__ off,
                                                      int* __restrict__ pos) {
    __shared__ int sc[256];
    int t = threadIdx.x;
    int i = blockIdx.x * 256 + t;
    int v = (i < Nn) ? deg[i] : 0;
    sc[t] = v;
    __syncthreads();
    for (int o = 1; o < 256; o <<= 1) {
        int u = (t >= o) ? sc[t - o] : 0;
        __syncthreads();
        sc[t] += u;
        __syncthreads();
    }
    int excl = sc[t] - v + boff[blockIdx.x];
    if (i < Nn) {
        off[i] = excl;
        pos[i] = excl;
    }
}

__global__ void scatter_kernel(const int* __restrict__ src, const int* __restrict__ dst,
                               const float* __restrict__ attr, int* __restrict__ pos,
                               int* __restrict__ ssrc, float* __restrict__ sattr) {
    int e = blockIdx.x * 256 + threadIdx.x;
    if (e < Ee) {
        int d = dst[e];
        int p = atomicAdd(&pos[d], 1);
        ssrc[p] = src[e];
        sattr[p] = attr[e];
    }
}

// ---------------- weight convert + transpose to bf16 [N][K] ----------------
// wt layout: [0, 65536)            proj  [256 n][256 k]  (n<128: lin_src col, else lin_dst)
//            [65536, 196608)       w1[l] [256 n][128 k]
//            [196608, 327680)      w2[l] [128 n][256 k]

__global__ void wconv_kernel(const float* __restrict__ lin_src_w,
                             const float* __restrict__ lin_dst_w,
                             const float* __restrict__ mlp_w1,
                             const float* __restrict__ mlp_w2,
                             unsigned short* __restrict__ wt) {
    int idx = blockIdx.x * 256 + threadIdx.x;
    if (idx >= 327680) return;
    float val;
    if (idx < 65536) {
        int n = idx >> 8, k = idx & 255;
        val = (n < 128) ? lin_src_w[k * 128 + n] : lin_dst_w[k * 128 + (n - 128)];
    } else if (idx < 196608) {
        int r = idx - 65536;
        int l = r >> 15, e = r & 32767;
        int n = e >> 7, k = e & 127;
        val = mlp_w1[(size_t)l * 32768 + k * 256 + n];
    } else {
        int r = idx - 196608;
        int l = r >> 15, e = r & 32767;
        int n = e >> 8, k = e & 255;
        val = mlp_w2[(size_t)l * 32768 + k * 128 + n];
    }
    wt[idx] = f2bf(val);
}

// ---------------- bf16 MFMA GEMM ----------------
// C[M,N] = A[M,K] @ B[N][K](bf16-transposed).  A fp32 (AF32) or bf16.
// mode: 0 = store bf16; 1 = BN+ReLU, store bf16; 2 = fp32 +=; 3 = fp32 store

#define BM 128
#define BN 64
#define BK 32
#define LDA 40
#define LDB 40

template <bool AF32>
__global__ __launch_bounds__(256) void gemm_kernel(
    const void* __restrict__ Aptr, const unsigned short* __restrict__ Bt,
    const float* __restrict__ bias, const float* __restrict__ bias2,
    const float* __restrict__ bn_g, const float* __restrict__ bn_b,
    const float* __restrict__ bn_m, const float* __restrict__ bn_v,
    float* __restrict__ CoutF, unsigned short* __restrict__ CoutB,
    int M, int N, int K, int mode) {
    __shared__ __align__(16) unsigned short As[BM * LDA];
    __shared__ __align__(16) unsigned short Bs[BN * LDB];
    int tid = threadIdx.x;
    int m0 = blockIdx.y * BM, n0 = blockIdx.x * BN;
    int wave = tid >> 6, lane = tid & 63;
    int wr = wave >> 1, wc = wave & 1;
    int lrow = lane & 15, quad = lane >> 4;

    f32x4 acc[4][2];
#pragma unroll
    for (int i = 0; i < 4; i++)
#pragma unroll
        for (int j = 0; j < 2; j++) acc[i][j] = (f32x4){0.f, 0.f, 0.f, 0.f};

    int bn_ = tid >> 2, bkb = (tid & 3) * 8;

    for (int k0 = 0; k0 < K; k0 += BK) {
        if (AF32) {
            const float* A = (const float*)Aptr;
            int arow = tid >> 1, akb = (tid & 1) * 16;
            int gr = m0 + arow;
            unsigned short tmp[16];
            if (gr < M) {
                const float* ap = A + (size_t)gr * K + k0 + akb;
                float4 v0 = ((const float4*)ap)[0];
                float4 v1 = ((const float4*)ap)[1];
                float4 v2 = ((const float4*)ap)[2];
                float4 v3 = ((const float4*)ap)[3];
                tmp[0] = f2bf(v0.x); tmp[1] = f2bf(v0.y); tmp[2] = f2bf(v0.z); tmp[3] = f2bf(v0.w);
                tmp[4] = f2bf(v1.x); tmp[5] = f2bf(v1.y); tmp[6] = f2bf(v1.z); tmp[7] = f2bf(v1.w);
                tmp[8] = f2bf(v2.x); tmp[9] = f2bf(v2.y); tmp[10] = f2bf(v2.z); tmp[11] = f2bf(v2.w);
                tmp[12] = f2bf(v3.x); tmp[13] = f2bf(v3.y); tmp[14] = f2bf(v3.z); tmp[15] = f2bf(v3.w);
            } else {
#pragma unroll
                for (int i = 0; i < 16; i++) tmp[i] = 0;
            }
            *(float4*)&As[arow * LDA + akb] = *(float4*)&tmp[0];
            *(float4*)&As[arow * LDA + akb + 8] = *(float4*)&tmp[8];
        } else {
            const unsigned short* A = (const unsigned short*)Aptr;
#pragma unroll
            for (int l2 = 0; l2 < 2; l2++) {
                int fi = tid + l2 * 256;
                int row = fi >> 2, kb = (fi & 3) * 8;
                int gr = m0 + row;
                short8 v = (short8){0, 0, 0, 0, 0, 0, 0, 0};
                if (gr < M) v = *(const short8*)(A + (size_t)gr * K + k0 + kb);
                *(short8*)&As[row * LDA + kb] = v;
            }
        }
        {
            const unsigned short* bp = Bt + (size_t)(n0 + bn_) * K + k0 + bkb;
            *(short8*)&Bs[bn_ * LDB + bkb] = *(const short8*)bp;
        }
        __syncthreads();
        short8 af[4], bf[2];
#pragma unroll
        for (int mt = 0; mt < 4; mt++) {
            int m = wr * 64 + mt * 16 + lrow;
            af[mt] = *(const short8*)&As[m * LDA + quad * 8];
        }
#pragma unroll
        for (int nt = 0; nt < 2; nt++) {
            int n = wc * 32 + nt * 16 + lrow;
            bf[nt] = *(const short8*)&Bs[n * LDB + quad * 8];
        }
#pragma unroll
        for (int mt = 0; mt < 4; mt++)
#pragma unroll
            for (int nt = 0; nt < 2; nt++)
                acc[mt][nt] = __builtin_amdgcn_mfma_f32_16x16x32_bf16(af[mt], bf[nt],
                                                                     acc[mt][nt], 0, 0, 0);
        __syncthreads();
    }

#pragma unroll
    for (int nt = 0; nt < 2; nt++) {
        int gc = n0 + wc * 32 + nt * 16 + lrow;
        float bs = (bias2 && gc >= 128) ? bias2[gc - 128] : (bias ? bias[gc] : 0.f);
        float g = 1.f, bb = 0.f, mm = 0.f, inv = 1.f;
        if (mode == 1) {
            g = bn_g[gc];
            bb = bn_b[gc];
            mm = bn_m[gc];
            inv = rsqrtf(bn_v[gc] + 1e-5f);
        }
#pragma unroll
        for (int mt = 0; mt < 4; mt++) {
#pragma unroll
            for (int r = 0; r < 4; r++) {
                int gr = m0 + wr * 64 + mt * 16 + quad * 4 + r;
                if (gr < M) {
                    float v = acc[mt][nt][r] + bs;
                    if (mode == 1) v = fmaxf(g * (v - mm) * inv + bb, 0.f);
                    size_t idx = (size_t)gr * N + gc;
                    if (mode <= 1)
                        CoutB[idx] = f2bf(v);
                    else if (mode == 2)
                        CoutF[idx] += v;
                    else
                        CoutF[idx] = v;
                }
            }
        }
    }
}

// ---------------- Fused GENConv aggregation (one-pass online softmax) ----------------

__global__ __launch_bounds__(128) void agg_kernel(
    const unsigned short* __restrict__ xs, int xss,
    const unsigned short* __restrict__ xd, int xds,
    const int* __restrict__ ssrc, const float* __restrict__ sattr,
    const int* __restrict__ off,
    const float* __restrict__ ew, const float* __restrict__ eb,
    const float* __restrict__ tptr, unsigned short* __restrict__ outb) {
    int d = blockIdx.x;
    int hh = threadIdx.x;
    int s0 = off[d], s1 = off[d + 1];
    float w = ew[hh], b = eb[hh];
    float tl = tptr[0];
    float mmax = -INFINITY, denom = 0.f, num = 0.f;

#define EDGE_STEP(xv, av)                                  \
    {                                                      \
        float msg = fmaxf((xv) + (av)*w + b, 0.f) + 1e-7f; \
        float z = msg * tl;                                \
        float nm = fmaxf(mmax, z);                         \
        float c = __expf(mmax - nm);                       \
        float e = __expf(z - nm);                          \
        denom = denom * c + e;                             \
        num = num * c + msg * e;                           \
        mmax = nm;                                         \
    }

    int j = s0;
    for (; j + 3 < s1; j += 4) {
        int i0 = ssrc[j], i1 = ssrc[j + 1], i2 = ssrc[j + 2], i3 = ssrc[j + 3];
        float a0 = sattr[j], a1 = sattr[j + 1], a2 = sattr[j + 2], a3 = sattr[j + 3];
        float x0 = bf2f(xs[(size_t)i0 * xss + hh]);
        float x1 = bf2f(xs[(size_t)i1 * xss + hh]);
        float x2 = bf2f(xs[(size_t)i2 * xss + hh]);
        float x3 = bf2f(xs[(size_t)i3 * xss + hh]);
        EDGE_STEP(x0, a0)
        EDGE_STEP(x1, a1)
        EDGE_STEP(x2, a2)
        EDGE_STEP(x3, a3)
    }
    for (; j < s1; j++) {
        int s = ssrc[j];
        float a = sattr[j];
        float xv = bf2f(xs[(size_t)s * xss + hh]);
        EDGE_STEP(xv, a)
    }
    float agg = (s1 > s0) ? (num / fmaxf(denom, 1e-16f)) : 0.f;
    outb[(size_t)d * Hh + hh] = f2bf(agg + bf2f(xd[(size_t)d * xds + hh]));
#undef EDGE_STEP
}

// ---------------- res+ pre-norm: r = relu(BN(h)) (bf16 out) ----------------

__global__ void prenorm_kernel(const float* __restrict__ h, const float* __restrict__ g,
                               const float* __restrict__ b, const float* __restrict__ m,
                               const float* __restrict__ v, unsigned short* __restrict__ r) {
    int idx = blockIdx.x * 256 + threadIdx.x;
    if (idx < Nn * Hh) {
        int hh = idx & (Hh - 1);
        float val = h[idx];
        val = g[hh] * (val - m[hh]) * rsqrtf(v[hh] + 1e-5f) + b[hh];
        r[idx] = f2bf(fmaxf(val, 0.f));
    }
}

// ---------------- final norm + hierarchical mean-pool ----------------

#define PCHUNK 100

__global__ __launch_bounds__(128) void pool_kernel(
    const float* __restrict__ h, const int* __restrict__ batch,
    const float* __restrict__ g, const float* __restrict__ b,
    const float* __restrict__ m, const float* __restrict__ v,
    float* __restrict__ pooled, float* __restrict__ cnt) {
    int hh = threadIdx.x;
    int i0 = blockIdx.x * PCHUNK;
    int i1 = min(i0 + PCHUNK, Nn);
    if (i0 >= Nn) return;
    float gg = g[hh], bb = b[hh], mm = m[hh], inv = rsqrtf(v[hh] + 1e-5f);
    int cur = batch[i0];
    float sum = 0.f, c = 0.f;
    for (int i = i0; i < i1; i++) {
        int gid = batch[i];
        float val = fmaxf(gg * (h[(size_t)i * Hh + hh] - mm) * inv + bb, 0.f);
        if (gid != cur) {
            atomicAdd(&pooled[(size_t)cur * Hh + hh], sum);
            if (hh == 0) atomicAdd(&cnt[cur], c);
            cur = gid;
            sum = 0.f;
            c = 0.f;
        }
        sum += val;
        c += 1.f;
    }
    atomicAdd(&pooled[(size_t)cur * Hh + hh], sum);
    if (hh == 0) atomicAdd(&cnt[cur], c);
}

// ---------------- classifier ----------------

__global__ __launch_bounds__(128) void cls_kernel(const float* __restrict__ pooled,
                                                  const float* __restrict__ cnt,
                                                  const float* __restrict__ clinical,
                                                  const float* __restrict__ w,
                                                  const float* __restrict__ bias,
                                                  float* __restrict__ out) {
    int t = threadIdx.x;
    int g = t >> 1, c = t & 1;
    float inv = 1.f / fmaxf(cnt[g], 1.f);
    float s = bias[c];
    for (int j = 0; j < Hh; j++) s += pooled[g * Hh + j] * inv * w[j * NCc + c];
    for (int k = 0; k < Kk; k++) s += clinical[g * Kk + k] * w[(Hh + k) * NCc + c];
    out[g * NCc + c] = s;
}

// ---------------- launch ----------------

extern "C" void kernel_launch(void* const* d_in, const int* in_sizes, int n_in,
                              void* d_out, int out_size, void* d_ws, size_t ws_size,
                              hipStream_t stream) {
    const float* x = (const float*)d_in[0];
    const int* eidx = (const int*)d_in[1];
    const float* eattr = (const float*)d_in[2];
    const int* batch = (const int*)d_in[3];
    const float* clinical = (const float*)d_in[4];
    const float* lin_src_w = (const float*)d_in[5];
    const float* lin_src_b = (const float*)d_in[6];
    const float* lin_dst_w = (const float*)d_in[7];
    const float* lin_dst_b = (const float*)d_in[8];
    const float* edge_w = (const float*)d_in[9];
    const float* edge_b = (const float*)d_in[10];
    const float* tt = (const float*)d_in[11];
    const float* mlp_w1 = (const float*)d_in[12];
    const float* mlp_b1 = (const float*)d_in[13];
    const float* bn_g = (const float*)d_in[14];
    const float* bn_b = (const float*)d_in[15];
    const float* bn_m = (const float*)d_in[16];
    const float* bn_v = (const float*)d_in[17];
    const float* mlp_w2 = (const float*)d_in[18];
    const float* mlp_b2 = (const float*)d_in[19];
    const float* norm_g = (const float*)d_in[20];
    const float* norm_b = (const float*)d_in[21];
    const float* norm_m = (const float*)d_in[22];
    const float* norm_v = (const float*)d_in[23];
    const float* cls_w = (const float*)d_in[24];
    const float* cls_b = (const float*)d_in[25];
    float* out = (float*)d_out;

    const int* src = eidx;
    const int* dst = eidx + Ee;

    char* ws = (char*)d_ws;
    size_t off_b = 0;
    auto alloc = [&](size_t bytes) -> void* {
        void* p = ws + off_b;
        off_b += (bytes + 255) & ~(size_t)255;
        return p;
    };
    unsigned short* xsd = (unsigned short*)alloc((size_t)Nn * 256 * 2);   // proj out
    unsigned short* rbuf = (unsigned short*)alloc((size_t)Nn * Hh * 2);   // prenorm out
    unsigned short* aggout = (unsigned short*)alloc((size_t)Nn * Hh * 2);
    unsigned short* hmid = (unsigned short*)alloc((size_t)Nn * 2 * Hh * 2);
    float* hbuf = (float*)alloc((size_t)Nn * Hh * 4);
    int* deg = (int*)alloc((Nn + 1) * 4);
    int* offp = (int*)alloc((Nn + 1) * 4);
    int* pos = (int*)alloc((size_t)Nn * 4);
    int* bsum = (int*)alloc(NB * 4);
    int* boff = (int*)alloc(NB * 4);
    int* ssrc = (int*)alloc((size_t)Ee * 4);
    float* sattr = (float*)alloc((size_t)Ee * 4);
    float* pooled = (float*)alloc((size_t)Gg * Hh * 4);
    float* cntb = (float*)alloc(Gg * 4);
    unsigned short* wt = (unsigned short*)alloc((size_t)327680 * 2);

    hipMemsetAsync(deg, 0, (Nn + 1) * 4, stream);
    hipMemsetAsync(pooled, 0, (size_t)Gg * Hh * 4, stream);
    hipMemsetAsync(cntb, 0, Gg * 4, stream);

    hist_kernel<<<(Ee + 255) / 256, 256, 0, stream>>>(dst, deg);
    bsum_kernel<<<NB, 256, 0, stream>>>(deg, bsum);
    bscan_kernel<<<1, 256, 0, stream>>>(bsum, boff, offp);
    offsets_kernel<<<NB, 256, 0, stream>>>(deg, boff, offp, pos);
    scatter_kernel<<<(Ee + 255) / 256, 256, 0, stream>>>(src, dst, eattr, pos, ssrc, sattr);
    wconv_kernel<<<1280, 256, 0, stream>>>(lin_src_w, lin_dst_w, mlp_w1, mlp_w2, wt);

    const unsigned short* wt_proj = wt;
    const unsigned short* wt_w1 = wt + 65536;
    const unsigned short* wt_w2 = wt + 196608;

    // Fused projection: xsd[:, :128] = x@Wsrc+b, xsd[:, 128:] = x@Wdst+b
    dim3 gproj(256 / BN, (Nn + BM - 1) / BM);
    gemm_kernel<true><<<gproj, 256, 0, stream>>>(x, wt_proj, lin_src_b, lin_dst_b, nullptr,
                                                 nullptr, nullptr, nullptr, nullptr, xsd, Nn,
                                                 256, Cc, 0);

    for (int l = 0; l < Ll; l++) {
        const unsigned short* cxs;
        const unsigned short* cxd;
        int xss, xds;
        if (l == 0) {
            cxs = xsd;
            xss = 256;
            cxd = xsd + 128;
            xds = 256;
        } else {
            prenorm_kernel<<<(Nn * Hh + 255) / 256, 256, 0, stream>>>(
                hbuf, norm_g + l * Hh, norm_b + l * Hh, norm_m + l * Hh, norm_v + l * Hh, rbuf);
            cxs = rbuf;
            xss = Hh;
            cxd = rbuf;
            xds = Hh;
        }
        agg_kernel<<<Nn, 128, 0, stream>>>(cxs, xss, cxd, xds, ssrc, sattr, offp,
                                           edge_w + l * Hh, edge_b + l * Hh, tt + l, aggout);
        dim3 g1((2 * Hh) / BN, (Nn + BM - 1) / BM);
        gemm_kernel<false><<<g1, 256, 0, stream>>>(aggout, wt_w1 + (size_t)l * 32768,
                                                   mlp_b1 + l * 2 * Hh, nullptr,
                                                   bn_g + l * 2 * Hh, bn_b + l * 2 * Hh,
                                                   bn_m + l * 2 * Hh, bn_v + l * 2 * Hh,
                                                   nullptr, hmid, Nn, 2 * Hh, Hh, 1);
        dim3 g2(Hh / BN, (Nn + BM - 1) / BM);
        gemm_kernel<false><<<g2, 256, 0, stream>>>(hmid, wt_w2 + (size_t)l * 32768,
                                                   mlp_b2 + l * Hh, nullptr, nullptr, nullptr,
                                                   nullptr, nullptr, hbuf, nullptr, Nn, Hh,
                                                   2 * Hh, (l == 0) ? 3 : 2);
    }

    pool_kernel<<<(Nn + PCHUNK - 1) / PCHUNK, 128, 0, stream>>>(hbuf, batch, norm_g, norm_b,
                                                                norm_m, norm_v, pooled, cntb);
    cls_kernel<<<1, 128, 0, stream>>>(pooled, cntb, clinical, cls_w, cls_b, out);
}